// Round 1
// baseline (208.981 us; speedup 1.0000x reference)
//
#include <hip/hip_runtime.h>
#include <hip/hip_bf16.h>
#include <cstdint>

typedef __bf16 bf16_t;
typedef __bf16 bf16x8 __attribute__((ext_vector_type(8)));
typedef __bf16 bf16x4 __attribute__((ext_vector_type(4)));
typedef float  f32x4  __attribute__((ext_vector_type(4)));

#define AS1 __attribute__((address_space(1)))
#define AS3 __attribute__((address_space(3)))

// async global->LDS, 16B per lane; LDS dest is wave-uniform base + lane*16
static __device__ __forceinline__ void gld_lds16(const void* g, void* l) {
  __builtin_amdgcn_global_load_lds((AS1 void*)g, (AS3 void*)l, 16, 0, 0);
}

// ---------------- convert / transpose ----------------

__global__ __launch_bounds__(256) void convert_f32_bf16(const float* __restrict__ in,
                                                        bf16_t* __restrict__ out, int n4) {
  int i = blockIdx.x * 256 + threadIdx.x;
  if (i < n4) {
    float4 v = ((const float4*)in)[i];
    bf16x4 o;
    o[0] = (bf16_t)v.x; o[1] = (bf16_t)v.y; o[2] = (bf16_t)v.z; o[3] = (bf16_t)v.w;
    *(bf16x4*)(out + (size_t)i * 4) = o;
  }
}

// in [K][N] f32 -> out [N][K] bf16
__global__ __launch_bounds__(256) void transpose_w(const float* __restrict__ in,
                                                   bf16_t* __restrict__ out, int K, int N) {
  __shared__ float tile[32][33];
  const int t = threadIdx.x, c = t & 31, r0 = t >> 5;
  const int bx = blockIdx.x, by = blockIdx.y;  // bx over N/32, by over K/32
#pragma unroll
  for (int i = 0; i < 4; ++i) {
    int r = r0 + i * 8;
    tile[r][c] = in[(size_t)(by * 32 + r) * N + bx * 32 + c];
  }
  __syncthreads();
#pragma unroll
  for (int i = 0; i < 4; ++i) {
    int r = r0 + i * 8;
    out[(size_t)(bx * 32 + r) * K + by * 32 + c] = (bf16_t)tile[c][r];
  }
}

// ---------------- 128x128 bf16 GEMM core (m97 structure, BK=32) ----------------
// A [M][K] row-major bf16, Bt [N][K] row-major bf16 (i.e. B transposed).
template <int KDIM>
static __device__ __forceinline__ void gemm128_compute(const bf16_t* __restrict__ A,
                                                       const bf16_t* __restrict__ Bt,
                                                       bf16_t* lA, bf16_t* lB,
                                                       f32x4 acc[4][4]) {
  const int t = threadIdx.x;
  const int lr = t & 15, g = (t >> 4) & 3;
  const int w = t >> 6, wr = w >> 1, wc = w & 1;
  const int bm = blockIdx.x, bn = blockIdx.y;

  for (int kt = 0; kt < KDIM; kt += 32) {
    __syncthreads();  // previous frag reads done before overwrite
#pragma unroll
    for (int c2 = 0; c2 < 2; ++c2) {
      const int idx = c2 * 256 + t;          // 0..511  -> row=idx>>2, 16B block=idx&3
      const int row = idx >> 2, cb = idx & 3;
      const int ldsoff = ((t & 192) + c2 * 256) * 8;  // wave-uniform element offset
      gld_lds16(A  + (size_t)(bm * 128 + row) * KDIM + kt + cb * 8, lA + ldsoff);
      gld_lds16(Bt + (size_t)(bn * 128 + row) * KDIM + kt + cb * 8, lB + ldsoff);
    }
    __syncthreads();  // vmcnt drained by barrier
    bf16x8 af[4], bv[4];
#pragma unroll
    for (int mi = 0; mi < 4; ++mi)
      af[mi] = *(const bf16x8*)(lA + (wr * 64 + mi * 16 + lr) * 32 + g * 8);
#pragma unroll
    for (int ni = 0; ni < 4; ++ni)
      bv[ni] = *(const bf16x8*)(lB + (wc * 64 + ni * 16 + lr) * 32 + g * 8);
#pragma unroll
    for (int mi = 0; mi < 4; ++mi)
#pragma unroll
      for (int ni = 0; ni < 4; ++ni)
        acc[mi][ni] = __builtin_amdgcn_mfma_f32_16x16x32_bf16(af[mi], bv[ni], acc[mi][ni], 0, 0, 0);
  }
}

// GEMM1: qkv = x @ Wqkv ; scatter into Q [bh][s][d], K [bh][s][d], Vt [bh][d][s] (bf16)
__global__ __launch_bounds__(256) void gemm_qkv_k(const bf16_t* __restrict__ xb,
                                                  const bf16_t* __restrict__ wt,
                                                  bf16_t* __restrict__ Qo,
                                                  bf16_t* __restrict__ Ko,
                                                  bf16_t* __restrict__ Vto) {
  __shared__ bf16_t lA[128 * 32], lB[128 * 32];
  f32x4 acc[4][4] = {};
  gemm128_compute<1024>(xb, wt, lA, lB, acc);
  const int t = threadIdx.x, lr = t & 15, g = (t >> 4) & 3, w = t >> 6, wr = w >> 1, wc = w & 1;
  const int row0 = blockIdx.x * 128 + wr * 64, col0 = blockIdx.y * 128 + wc * 64;
#pragma unroll
  for (int mi = 0; mi < 4; ++mi) {
    const int row = row0 + mi * 16 + g * 4;  // + r
    const int b = row >> 11, s = row & 2047;
#pragma unroll
    for (int ni = 0; ni < 4; ++ni) {
      const int col = col0 + ni * 16 + lr;
      const int t3 = col >> 10, rem = col & 1023, h = rem >> 6, d = rem & 63;
      const int bh = b * 16 + h;
#pragma unroll
      for (int r = 0; r < 4; ++r) {
        const bf16_t v = (bf16_t)acc[mi][ni][r];
        if (t3 == 0)      Qo[((size_t)bh * 2048 + s + r) * 64 + d] = v;
        else if (t3 == 1) Ko[((size_t)bh * 2048 + s + r) * 64 + d] = v;
        else              Vto[((size_t)bh * 64 + d) * 2048 + s + r] = v;
      }
    }
  }
}

// GEMM3: out = attn @ Wo  (fp32 out)
__global__ __launch_bounds__(256) void gemm_o_k(const bf16_t* __restrict__ attn,
                                                const bf16_t* __restrict__ wot,
                                                float* __restrict__ out) {
  __shared__ bf16_t lA[128 * 32], lB[128 * 32];
  f32x4 acc[4][4] = {};
  gemm128_compute<1024>(attn, wot, lA, lB, acc);
  const int t = threadIdx.x, lr = t & 15, g = (t >> 4) & 3, w = t >> 6, wr = w >> 1, wc = w & 1;
  const int row0 = blockIdx.x * 128 + wr * 64, col0 = blockIdx.y * 128 + wc * 64;
#pragma unroll
  for (int mi = 0; mi < 4; ++mi) {
    const int row = row0 + mi * 16 + g * 4;
#pragma unroll
    for (int ni = 0; ni < 4; ++ni) {
      const int col = col0 + ni * 16 + lr;
#pragma unroll
      for (int r = 0; r < 4; ++r)
        out[(size_t)(row + r) * 1024 + col] = acc[mi][ni][r];
    }
  }
}

// ---------------- flash attention ----------------
// grid (16, 32): x = 128-row q block, y = bh. 4 waves * 32 q-rows.
// Q,K: [bh][2048][64] bf16 ; Vt: [bh][64][2048] bf16 ; O: [b][s][h*64+d] bf16
__global__ __launch_bounds__(256) void attn_k(const bf16_t* __restrict__ Q,
                                              const bf16_t* __restrict__ K,
                                              const bf16_t* __restrict__ Vt,
                                              bf16_t* __restrict__ O) {
  __shared__ bf16_t pbuf[4][2][16 * 32];
  const int t = threadIdx.x, w = t >> 6, l = t & 63, g = l >> 4, lr = l & 15;
  const int bh = blockIdx.y, b = bh >> 4, h = bh & 15;
  const bf16_t* Qb = Q + (size_t)bh * 2048 * 64;
  const bf16_t* Kb = K + (size_t)bh * 2048 * 64;
  const bf16_t* Vb = Vt + (size_t)bh * 64 * 2048;
  const int q0 = blockIdx.x * 128 + w * 32;
  const float cs = 0.18033688011112042f;  // log2(e)/sqrt(64)

  bf16x8 aq[2][2];
#pragma unroll
  for (int iq = 0; iq < 2; ++iq) {
    const bf16_t* qp = Qb + (size_t)(q0 + iq * 16 + lr) * 64;
    aq[iq][0] = *(const bf16x8*)(qp + g * 8);
    aq[iq][1] = *(const bf16x8*)(qp + 32 + g * 8);
  }
  f32x4 o[2][4] = {};
  float m[2][4], ls[2][4];
#pragma unroll
  for (int iq = 0; iq < 2; ++iq)
#pragma unroll
    for (int r = 0; r < 4; ++r) { m[iq][r] = -1e30f; ls[iq][r] = 0.0f; }

  for (int jt = 0; jt < 64; ++jt) {
    const int k0 = jt * 32;
    bf16x8 bk[2][2];
#pragma unroll
    for (int h2 = 0; h2 < 2; ++h2) {
      const bf16_t* kp = Kb + (size_t)(k0 + h2 * 16 + lr) * 64;
      bk[h2][0] = *(const bf16x8*)(kp + g * 8);
      bk[h2][1] = *(const bf16x8*)(kp + 32 + g * 8);
    }
#pragma unroll
    for (int iq = 0; iq < 2; ++iq) {
      f32x4 s0 = {}, s1 = {};
      s0 = __builtin_amdgcn_mfma_f32_16x16x32_bf16(aq[iq][0], bk[0][0], s0, 0, 0, 0);
      s0 = __builtin_amdgcn_mfma_f32_16x16x32_bf16(aq[iq][1], bk[0][1], s0, 0, 0, 0);
      s1 = __builtin_amdgcn_mfma_f32_16x16x32_bf16(aq[iq][0], bk[1][0], s1, 0, 0, 0);
      s1 = __builtin_amdgcn_mfma_f32_16x16x32_bf16(aq[iq][1], bk[1][1], s1, 0, 0, 0);
      float alpha[4];
#pragma unroll
      for (int r = 0; r < 4; ++r) {
        float v0 = s0[r] * cs, v1 = s1[r] * cs;
        float mx = fmaxf(v0, v1);
#pragma unroll
        for (int msk = 1; msk < 16; msk <<= 1) mx = fmaxf(mx, __shfl_xor(mx, msk));
        float mn = fmaxf(m[iq][r], mx);
        alpha[r] = exp2f(m[iq][r] - mn);
        m[iq][r] = mn;
        float p0 = exp2f(v0 - mn), p1 = exp2f(v1 - mn);
        ls[iq][r] = ls[iq][r] * alpha[r] + p0 + p1;
        pbuf[w][iq][(g * 4 + r) * 32 + lr] = (bf16_t)p0;
        pbuf[w][iq][(g * 4 + r) * 32 + 16 + lr] = (bf16_t)p1;
      }
#pragma unroll
      for (int nt = 0; nt < 4; ++nt)
#pragma unroll
        for (int r = 0; r < 4; ++r) o[iq][nt][r] *= alpha[r];
    }
    bf16x8 ap0 = *(const bf16x8*)(&pbuf[w][0][lr * 32 + g * 8]);
    bf16x8 ap1 = *(const bf16x8*)(&pbuf[w][1][lr * 32 + g * 8]);
#pragma unroll
    for (int nt = 0; nt < 4; ++nt) {
      bf16x8 bvv = *(const bf16x8*)(Vb + (size_t)(nt * 16 + lr) * 2048 + k0 + g * 8);
      o[0][nt] = __builtin_amdgcn_mfma_f32_16x16x32_bf16(ap0, bvv, o[0][nt], 0, 0, 0);
      o[1][nt] = __builtin_amdgcn_mfma_f32_16x16x32_bf16(ap1, bvv, o[1][nt], 0, 0, 0);
    }
  }
#pragma unroll
  for (int iq = 0; iq < 2; ++iq) {
    float inv[4];
#pragma unroll
    for (int r = 0; r < 4; ++r) {
      float s = ls[iq][r];
#pragma unroll
      for (int msk = 1; msk < 16; msk <<= 1) s += __shfl_xor(s, msk);
      inv[r] = 1.0f / s;
    }
#pragma unroll
    for (int nt = 0; nt < 4; ++nt)
#pragma unroll
      for (int r = 0; r < 4; ++r) {
        const int row = q0 + iq * 16 + g * 4 + r;
        const int col = h * 64 + nt * 16 + lr;
        O[((size_t)b * 2048 + row) * 1024 + col] = (bf16_t)(o[iq][nt][r] * inv[r]);
      }
  }
}

// ---------------- launcher ----------------

extern "C" void kernel_launch(void* const* d_in, const int* in_sizes, int n_in,
                              void* d_out, int out_size, void* d_ws, size_t ws_size,
                              hipStream_t stream) {
  const float* x    = (const float*)d_in[0];  // [2,2048,1024]
  const float* wqkv = (const float*)d_in[1];  // [1024,3072]
  const float* wo   = (const float*)d_in[2];  // [1024,1024]
  float* out = (float*)d_out;

  char* ws = (char*)d_ws;
  bf16_t* xb    = (bf16_t*)(ws);                       // 8 MB  [4096][1024]
  bf16_t* wqkvT = (bf16_t*)(ws + (size_t)(8u  << 20)); // 6 MB  [3072][1024]
  bf16_t* woT   = (bf16_t*)(ws + (size_t)(14u << 20)); // 2 MB  [1024][1024]
  bf16_t* Qb    = (bf16_t*)(ws + (size_t)(16u << 20)); // 8 MB  [32][2048][64]
  bf16_t* Kb    = (bf16_t*)(ws + (size_t)(24u << 20)); // 8 MB
  bf16_t* Vtb   = (bf16_t*)(ws + (size_t)(32u << 20)); // 8 MB  [32][64][2048]
  bf16_t* attn  = (bf16_t*)(ws + (size_t)(40u << 20)); // 8 MB  [4096][1024]

  convert_f32_bf16<<<4096, 256, 0, stream>>>(x, xb, 4096 * 1024 / 4);
  transpose_w<<<dim3(96, 32), 256, 0, stream>>>(wqkv, wqkvT, 1024, 3072);
  transpose_w<<<dim3(32, 32), 256, 0, stream>>>(wo, woT, 1024, 1024);
  gemm_qkv_k<<<dim3(32, 24), 256, 0, stream>>>(xb, wqkvT, Qb, Kb, Vtb);
  attn_k<<<dim3(16, 32), 256, 0, stream>>>(Qb, Kb, Vtb, attn);
  gemm_o_k<<<dim3(32, 8), 256, 0, stream>>>(attn, woT, out);
}